// Round 3
// baseline (271.827 us; speedup 1.0000x reference)
//
#include <hip/hip_runtime.h>
#include <hip/hip_bf16.h>

using bf16 = __hip_bfloat16;
typedef __bf16 bf16x8 __attribute__((ext_vector_type(8)));
typedef float f32x4 __attribute__((ext_vector_type(4)));

#define MT 32          // tokens per block
#define SX 136         // xs row stride (elems): 128 + 8 pad  (272 B)
#define SH 264         // hs row stride: 256 + 8              (528 B)
#define SN 552         // ns row stride: 544 + 8              (1104 B)
#define SM 40          // ms row stride: 32 + 8               (80 B)
// LDS element offsets (bf16 elems):
//   xs: [32][136] at 0        (4352 elems)
//   hs: [32][264] at 4352     (8448 elems)  -> region 0..12800
//   ms: [272][40] at 0        (10880 elems) -> overlaps xs+hs (dead by then)
//   ns: [32][552] at 12800    (17664 elems)
// total 30464 elems = 60928 B  -> 2 blocks/CU

__device__ __forceinline__ float bf2f(bf16 v) { return __bfloat162float(v); }

__device__ __forceinline__ float gelu_f(float x) {
    // tanh-approx GELU; |err vs erf-gelu| <= ~3e-3 abs, fine vs 2%-of-max threshold
    float u  = 0.7978845608f * x * (1.0f + 0.044715f * x * x);
    float au = fabsf(u);
    float e  = __expf(-2.0f * au);
    float t  = (1.0f - e) / (1.0f + e);
    t = (u < 0.0f) ? -t : t;
    return 0.5f * x * (1.0f + t);
}

__device__ __forceinline__ bf16x8 ld8(const bf16* p) {
    return *reinterpret_cast<const bf16x8*>(p);
}
__device__ __forceinline__ f32x4 mfma16(bf16x8 a, bf16x8 b, f32x4 c) {
    return __builtin_amdgcn_mfma_f32_16x16x32_bf16(a, b, c, 0, 0, 0);
}

// ---------------- prep: fp32 weights -> transposed bf16; softmax adjacency ----------------
// W1T 128x256 -> [256][128] | W2T 256x544 -> [544][256] | Wg1T, Wg2T 32x32 -> [n][k]
__global__ void prep_kernel(const float* __restrict__ W1, const float* __restrict__ W2,
                            const float* __restrict__ Wg1, const float* __restrict__ Wg2,
                            const float* __restrict__ adj1, const float* __restrict__ adj2,
                            bf16* __restrict__ w1t, bf16* __restrict__ w2t,
                            bf16* __restrict__ wg1t, bf16* __restrict__ wg2t,
                            float* __restrict__ A1f, float* __restrict__ A2f) {
    int idx = blockIdx.x * 256 + threadIdx.x;
    if (idx < 32768) {                       // W1: r=k(128), c=n(256)
        int r = idx >> 8, c = idx & 255;
        w1t[c * 128 + r] = __float2bfloat16(W1[idx]);
    } else if (idx < 172032) {               // W2: r=k(256), c=n(544)
        int j = idx - 32768;
        int r = j / 544, c = j % 544;
        w2t[c * 256 + r] = __float2bfloat16(W2[j]);
    } else if (idx < 173056) {
        int j = idx - 172032;
        wg1t[(j & 31) * 32 + (j >> 5)] = __float2bfloat16(Wg1[j]);
    } else if (idx < 174080) {
        int j = idx - 173056;
        wg2t[(j & 31) * 32 + (j >> 5)] = __float2bfloat16(Wg2[j]);
    }
    if (blockIdx.x == 0) {
        int t = threadIdx.x;
        if (t < 17 || (t >= 32 && t < 49)) {
            const float* adj = (t < 17) ? adj1 : adj2;
            float*       A   = (t < 17) ? A1f  : A2f;
            int row = (t < 17) ? t : (t - 32);
            float v[17]; float mx = -1e30f;
            for (int j = 0; j < 17; ++j) { v[j] = adj[row * 17 + j]; mx = fmaxf(mx, v[j]); }
            float s = 0.0f;
            for (int j = 0; j < 17; ++j) { v[j] = __expf(v[j] - mx); s += v[j]; }
            float inv = 1.0f / s;
            for (int j = 0; j < 17; ++j) A[row * 17 + j] = v[j] * inv;
        }
    }
}

// ---------------- main fused kernel ----------------
__global__ __launch_bounds__(256, 2)
void gat_main(const float* __restrict__ x,
              const float* __restrict__ b1, const float* __restrict__ b2,
              const float* __restrict__ bg1, const float* __restrict__ bg2,
              const bf16* __restrict__ w1t, const bf16* __restrict__ w2t,
              const bf16* __restrict__ wg1t, const bf16* __restrict__ wg2t,
              const float* __restrict__ A1, const float* __restrict__ A2,
              const float* __restrict__ Wc, const float* __restrict__ bc,
              float* __restrict__ out) {
    __shared__ alignas(16) bf16 lds[30464];
    bf16* xs = lds;            // [32][SX]
    bf16* hs = lds + 4352;     // [32][SH]
    bf16* ms = lds;            // [272][SM] (reuses xs+hs region)
    bf16* ns = lds + 12800;    // [32][SN]

    const int tid  = threadIdx.x;
    const int w    = tid >> 6;
    const int lane = tid & 63;
    const int l    = lane & 15;   // tile row (A) / col (B, C/D)
    const int q    = lane >> 4;   // quad
    const int t0   = blockIdx.x * MT;

    // ---- stage x tile (fp32 -> bf16): 32 rows x 32 float4-chunks ----
    for (int c = tid; c < 1024; c += 256) {
        int row = c >> 5, c4 = c & 31;
        const float4 v = *reinterpret_cast<const float4*>(x + (size_t)(t0 + row) * 128 + c4 * 4);
        bf16 tmp[4] = { __float2bfloat16(v.x), __float2bfloat16(v.y),
                        __float2bfloat16(v.z), __float2bfloat16(v.w) };
        *reinterpret_cast<ushort4*>(xs + row * SX + c4 * 4) =
            *reinterpret_cast<const ushort4*>(tmp);
    }
    __syncthreads();

    // ---- GEMM1: h = gelu(x @ W1 + b1)  [32,128]@[128,256] ----
    for (int nt = w * 4; nt < w * 4 + 4; ++nt) {
        int n = nt * 16 + l;
        bf16x8 bfr[4];
        const bf16* wp = w1t + n * 128 + q * 8;
#pragma unroll
        for (int kf = 0; kf < 4; ++kf) bfr[kf] = ld8(wp + kf * 32);
        float bias = b1[n];
#pragma unroll
        for (int mt = 0; mt < 2; ++mt) {
            f32x4 acc = {0.f, 0.f, 0.f, 0.f};
            const bf16* ap = xs + (mt * 16 + l) * SX + q * 8;
#pragma unroll
            for (int kf = 0; kf < 4; ++kf)
                acc = mfma16(ld8(ap + kf * 32), bfr[kf], acc);
            int trow = mt * 16 + q * 4;
#pragma unroll
            for (int r = 0; r < 4; ++r)
                hs[(trow + r) * SH + n] = __float2bfloat16(gelu_f(acc[r] + bias));
        }
    }
    __syncthreads();

    // ---- GEMM2: nodes = h @ W2 + b2  [32,256]@[256,544] ----
    for (int nt = w; nt < 34; nt += 4) {
        int n = nt * 16 + l;
        bf16x8 bfr[8];
        const bf16* wp = w2t + n * 256 + q * 8;
#pragma unroll
        for (int kf = 0; kf < 8; ++kf) bfr[kf] = ld8(wp + kf * 32);
        float bias = b2[n];
#pragma unroll
        for (int mt = 0; mt < 2; ++mt) {
            f32x4 acc = {0.f, 0.f, 0.f, 0.f};
            const bf16* ap = hs + (mt * 16 + l) * SH + q * 8;
#pragma unroll
            for (int kf = 0; kf < 8; ++kf)
                acc = mfma16(ld8(ap + kf * 32), bfr[kf], acc);
            int trow = mt * 16 + q * 4;
#pragma unroll
            for (int r = 0; r < 4; ++r)
                ns[(trow + r) * SN + n] = __float2bfloat16(acc[r] + bias);
        }
    }
    __syncthreads();

    // ---- two GAT blocks ----
    for (int g = 0; g < 2; ++g) {
        const float* A   = g ? A2 : A1;       // fp32 softmaxed adjacency (wave-uniform reads)
        const bf16* wgt  = g ? wg2t : wg1t;
        const float* bg  = g ? bg2 : bg1;
        bf16x8 wfr[2];
#pragma unroll
        for (int nt = 0; nt < 2; ++nt) wfr[nt] = ld8(wgt + (nt * 16 + l) * 32 + q * 8);
        float bgf[2] = { bg[l], bg[16 + l] };

        for (int half = 0; half < 2; ++half) {
            // mixing: thread -> (token-in-half = tid>>4, feature-pair f0 = (tid&15)*2)
            {
                int th   = tid >> 4;
                int tloc = half * 16 + th;
                int f0   = (tid & 15) * 2;
                float v0[17], v1[17];
                const bf16* npt = ns + tloc * SN + f0;
#pragma unroll
                for (int j = 0; j < 17; ++j) {
                    __hip_bfloat162 p = *reinterpret_cast<const __hip_bfloat162*>(npt + j * 32);
                    v0[j] = bf2f(p.x); v1[j] = bf2f(p.y);
                }
                for (int i = 0; i < 17; ++i) {
                    float m0 = 0.f, m1 = 0.f;
#pragma unroll
                    for (int j = 0; j < 17; ++j) {
                        float a = A[i * 17 + j];
                        m0 = fmaf(a, v0[j], m0);
                        m1 = fmaf(a, v1[j], m1);
                    }
                    __hip_bfloat162 pr;
                    pr.x = __float2bfloat16(m0); pr.y = __float2bfloat16(m1);
                    *reinterpret_cast<__hip_bfloat162*>(ms + (th * 17 + i) * SM + f0) = pr;
                }
            }
            __syncthreads();

            // Wg GEMM over 272 rows (17 M-tiles), N=32 (2 tiles), K=32; gelu + residual
            for (int mt = w; mt < 17; mt += 4) {
                const bf16* ap = ms + (mt * 16 + l) * SM + q * 8;
                bf16x8 afr = ld8(ap);
#pragma unroll
                for (int nt = 0; nt < 2; ++nt) {
                    f32x4 acc = {0.f, 0.f, 0.f, 0.f};
                    acc = mfma16(afr, wfr[nt], acc);
                    int f = nt * 16 + l;
#pragma unroll
                    for (int r = 0; r < 4; ++r) {
                        int rloc = mt * 16 + q * 4 + r;       // 0..271
                        int t    = half * 16 + rloc / 17;     // token in block
                        int i    = rloc % 17;
                        int off  = t * SN + i * 32 + f;
                        float nv = bf2f(ns[off]);
                        ns[off]  = __float2bfloat16(gelu_f(acc[r] + bgf[nt]) + nv);
                    }
                }
            }
            __syncthreads();
        }
    }

    // ---- coord projection: out = g2 @ Wc + bc (fp32 output!) ----
    for (int r = tid; r < 544; r += 256) {
        int t = r / 17, i = r % 17;
        const __hip_bfloat162* gp = reinterpret_cast<const __hip_bfloat162*>(ns + t * SN + i * 32);
        float o0 = bc[0], o1 = bc[1];
#pragma unroll
        for (int k2 = 0; k2 < 16; ++k2) {
            __hip_bfloat162 p = gp[k2];
            float a = bf2f(p.x), b = bf2f(p.y);
            int k = k2 * 2;
            o0 = fmaf(a, Wc[k * 2 + 0], o0);
            o1 = fmaf(a, Wc[k * 2 + 1], o1);
            o0 = fmaf(b, Wc[k * 2 + 2], o0);
            o1 = fmaf(b, Wc[k * 2 + 3], o1);
        }
        float2 pr = { o0, o1 };
        reinterpret_cast<float2*>(out)[(size_t)(t0 + t) * 17 + i] = pr;
    }
}

extern "C" void kernel_launch(void* const* d_in, const int* in_sizes, int n_in,
                              void* d_out, int out_size, void* d_ws, size_t ws_size,
                              hipStream_t stream) {
    const float* x    = (const float*)d_in[0];
    const float* W1   = (const float*)d_in[1];
    const float* b1   = (const float*)d_in[2];
    const float* W2   = (const float*)d_in[3];
    const float* b2   = (const float*)d_in[4];
    const float* adj1 = (const float*)d_in[5];
    const float* Wg1  = (const float*)d_in[6];
    const float* bg1  = (const float*)d_in[7];
    const float* adj2 = (const float*)d_in[8];
    const float* Wg2  = (const float*)d_in[9];
    const float* bg2  = (const float*)d_in[10];
    const float* Wc   = (const float*)d_in[11];
    const float* bc   = (const float*)d_in[12];

    char* ws = (char*)d_ws;
    bf16*  w1t  = (bf16*)(ws + 0);        // 65536 B
    bf16*  w2t  = (bf16*)(ws + 65536);    // 278528 B
    bf16*  wg1t = (bf16*)(ws + 344064);   // 2048 B
    bf16*  wg2t = (bf16*)(ws + 346112);   // 2048 B
    float* A1f  = (float*)(ws + 348160);  // 1156 B
    float* A2f  = (float*)(ws + 349376);  // 1156 B

    prep_kernel<<<680, 256, 0, stream>>>(W1, W2, Wg1, Wg2, adj1, adj2,
                                         w1t, w2t, wg1t, wg2t, A1f, A2f);

    const int tokens = 16 * 4096;
    gat_main<<<tokens / MT, 256, 0, stream>>>(x, b1, b2, bg1, bg2,
                                              w1t, w2t, wg1t, wg2t,
                                              A1f, A2f, Wc, bc, (float*)d_out);
}